// Round 17
// baseline (82.657 us; speedup 1.0000x reference)
//
#include <hip/hip_runtime.h>
#include <math.h>

#define EMB 8
#define SEQ 1024
#define NBATCH 32
#define NROWS (NBATCH * SEQ)
#define LNEPS 1e-5f
#define F(l, b, c) (((l) * 32 + (b)) * 16 + (c))

typedef __attribute__((ext_vector_type(4))) unsigned u32x4;
typedef __attribute__((ext_vector_type(8))) _Float16 f16x8;
typedef __attribute__((ext_vector_type(16))) float f32x16;

union FragU { unsigned u[4]; f16x8 s; };

__device__ __forceinline__ unsigned pkrtz(float a, float b) {
    unsigned r;
    asm("v_cvt_pkrtz_f16_f32 %0, %1, %2" : "=v"(r) : "v"(a), "v"(b));
    return r;
}
__device__ __forceinline__ unsigned pk_mul_f16(unsigned a, unsigned b) {
    unsigned r;
    asm("v_pk_mul_f16 %0, %1, %2" : "=v"(r) : "v"(a), "v"(b));
    return r;
}
// Bare hardware 2^x (v_exp_f32) — R13-proven 25 µs win vs __ocml_exp2_f32.
__device__ __forceinline__ float hw_exp2(float x) {
    return __builtin_amdgcn_exp2f(x);
}

// LLC-coherent (sc0 sc1) accessors: bypass L1/L2, land at the cross-XCD
// coherence point. No cache-wide maintenance anywhere.
// Load 2 rows from each of two batches; single vmcnt drain.
__device__ __forceinline__ void llc_load_2x2(const unsigned short* pa,
                                             const unsigned short* pb,
                                             u32x4* a0, u32x4* a1,
                                             u32x4* b0, u32x4* b1) {
    asm volatile(
        "global_load_dwordx4 %0, %[a], off sc0 sc1\n\t"
        "global_load_dwordx4 %1, %[a], off offset:16 sc0 sc1\n\t"
        "global_load_dwordx4 %2, %[b], off sc0 sc1\n\t"
        "global_load_dwordx4 %3, %[b], off offset:16 sc0 sc1\n\t"
        "s_waitcnt vmcnt(0)"
        : "=&v"(*a0), "=&v"(*a1), "=&v"(*b0), "=&v"(*b1)
        : [a] "v"(pa), [b] "v"(pb) : "memory");
}
// Poll two producer flags with one wait per iteration.
__device__ __forceinline__ void poll2(const unsigned* p0, const unsigned* p1) {
    unsigned f0, f1;
    for (;;) {
        asm volatile(
            "global_load_dword %0, %2, off sc0 sc1\n\t"
            "global_load_dword %1, %3, off sc0 sc1\n\t"
            "s_waitcnt vmcnt(0)"
            : "=&v"(f0), "=&v"(f1) : "v"(p0), "v"(p1) : "memory");
        if (f0 != 0u && f1 != 0u) break;
        __builtin_amdgcn_s_sleep(1);
    }
}
__device__ __forceinline__ void llc_store_row16(unsigned short* p, u32x4 v) {
    asm volatile("global_store_dwordx4 %[a], %[x], off sc0 sc1"
                 :: [a] "v"(p), [x] "v"(v) : "memory");
}
__device__ __forceinline__ void sys_store(float* p, float v) {
    asm volatile("global_store_dword %0, %1, off sc0 sc1" :: "v"(p), "v"(v) : "memory");
}
__device__ __forceinline__ float sys_load(const float* p) {
    float r;
    asm volatile("global_load_dword %0, %1, off sc0 sc1\n\ts_waitcnt vmcnt(0)"
                 : "=v"(r) : "v"(p) : "memory");
    return r;
}
__device__ __forceinline__ void sys_store_u32(unsigned* p, unsigned v) {
    asm volatile("global_store_dword %0, %1, off sc0 sc1" :: "v"(p), "v"(v) : "memory");
}

// Closed-form quantum head: RX layer + Clifford (CNOT chain + H) conjugates
// each Z_i into a product of cos(x_j) (even/odd prefix products).
__device__ __forceinline__ void qhead(const float xv[8], float z[8]) {
    float c[8];
#pragma unroll
    for (int j = 0; j < 8; ++j) c[j] = __cosf(xv[j]);
    float e0 = c[0];
    float o1 = c[1];
    float e2 = e0 * c[2];
    float o3 = o1 * c[3];
    float e4 = e2 * c[4];
    float o5 = o3 * c[5];
    float e6 = e4 * c[6];
    z[0] = e0; z[1] = o1; z[2] = e2; z[3] = o3;
    z[4] = e4; z[5] = o5; z[6] = e6;
    z[7] = e6 * o5 * c[7];
}

__device__ __forceinline__ void embed_row(const int* __restrict__ tokens,
                                          const float* __restrict__ emb,
                                          long grow, int srow, float xv[8]) {
    int tok = tokens[grow];
    const float* e = emb + (long)tok * EMB;
    float p = (float)srow;
    xv[0] = e[0] + sinf(p);
    xv[1] = e[1] + cosf(p);
    xv[2] = e[2] + sinf(p * 0.1f);
    xv[3] = e[3] + cosf(p * 0.1f);
    xv[4] = e[4] + sinf(p * 0.01f);
    xv[5] = e[5] + cosf(p * 0.01f);
    xv[6] = e[6] + sinf(p * 0.001f);
    xv[7] = e[7] + cosf(p * 0.001f);
}

__device__ __forceinline__ u32x4 pack_row(const float z[8]) {
    u32x4 d;
    d[0] = pkrtz(z[0], z[1]); d[1] = pkrtz(z[2], z[3]);
    d[2] = pkrtz(z[4], z[5]); d[3] = pkrtz(z[6], z[7]);
    return d;
}

// Flags must be zero at kernel start each call (harness poisons ws once).
__global__ __launch_bounds__(1024) void zero_flags(unsigned* __restrict__ f) {
    for (int i = threadIdx.x; i < 3584; i += 1024) f[i] = 0u;
}

// Whole model, one persistent kernel, MERGED per-layer phase (vs R16's 2):
// stage both batches (one vmcnt) -> barrier -> MFMA 16 tiles (both phases)
// -> barrier -> BOTH epilogues concurrently on waves 0,1.  Per layer: 2
// barriers (was 4), 1 stage-latency exposure (was 2), epi exposed once.
// Grid 256 WGs x 512 thr (1 WG/CU, all co-resident => deadlock-free);
// cross-WG sync: per-producer sc0sc1 flags (R11-proven).
__global__ __launch_bounds__(512, 2) void qt_fused(
    const int* __restrict__ tokens, const float* __restrict__ emb,
    const float* __restrict__ attn_w, const float* __restrict__ attn_b,
    const float* __restrict__ ln1_g, const float* __restrict__ ln1_b,
    const float* __restrict__ ffn_w1, const float* __restrict__ ffn_b1,
    const float* __restrict__ ffn_w2, const float* __restrict__ ffn_b2,
    const float* __restrict__ ln2_g, const float* __restrict__ ln2_b,
    const float* __restrict__ cls_w, const float* __restrict__ cls_b,
    unsigned short* __restrict__ qkv0, unsigned short* __restrict__ qkv1,
    unsigned* __restrict__ flags, unsigned* __restrict__ pcnt,
    float* __restrict__ partial, float* __restrict__ out)
{
    __shared__ __align__(16) uint2 KbP[2][2][1024];          // 32 KB fp16(z) [ph][h][row]
    __shared__ __align__(16) unsigned short VtH[2][8][1032]; // 33 KB transposed
    __shared__ float Olds[2][8][32][9];                      // 18.4 KB PV partials
    __shared__ float x_lds[2][64][8];                        // 4 KB residual stream
    __shared__ int isL[2];

    const int bid = blockIdx.x;
    const int group = bid & 15;     // group's 16 WGs share an XCD (round-robin)
    const int chunk = bid >> 4;     // 0..15, rows [chunk*64, chunk*64+64)
    const int tid = threadIdx.x;

    const int w = tid >> 6;
    const int lane = tid & 63;
    const int ln = lane & 31;
    const int h = lane >> 5;
    const int qtile = w >> 2;       // 0..1
    const int qu = w & 3;           // key quarter
    const int r0 = tid * 2;         // this thread's 2 staging rows (per batch)
    const int bb0 = group * 2, bb1 = bb0 + 1;
    const unsigned B2PK = pkrtz(0.51006972f, 0.51006972f);  // log2e/sqrt(8)

    for (int l = 0; l < 6; ++l) {
        const unsigned short* qr = (l & 1) ? qkv1 : qkv0;
        unsigned short* qw = (l & 1) ? qkv0 : qkv1;

        // ---------------- stage BOTH batches: rows r0, r0+1 ----------------
        {
            u32x4 dA0, dA1, dB0, dB1;
            if (l == 0) {
                const int inX = ((r0 >> 6) == chunk);
                const int lr = r0 - chunk * 64;
                float e[8], z[8];
                embed_row(tokens, emb, (long)bb0 * SEQ + r0, r0, e);
                if (inX) { for (int j = 0; j < 8; ++j) x_lds[0][lr][j] = e[j]; }
                qhead(e, z); dA0 = pack_row(z);
                embed_row(tokens, emb, (long)bb0 * SEQ + r0 + 1, r0 + 1, e);
                if (inX) { for (int j = 0; j < 8; ++j) x_lds[0][lr + 1][j] = e[j]; }
                qhead(e, z); dA1 = pack_row(z);
                embed_row(tokens, emb, (long)bb1 * SEQ + r0, r0, e);
                if (inX) { for (int j = 0; j < 8; ++j) x_lds[1][lr][j] = e[j]; }
                qhead(e, z); dB0 = pack_row(z);
                embed_row(tokens, emb, (long)bb1 * SEQ + r0 + 1, r0 + 1, e);
                if (inX) { for (int j = 0; j < 8; ++j) x_lds[1][lr + 1][j] = e[j]; }
                qhead(e, z); dB1 = pack_row(z);
            } else {
                poll2(&flags[F(l, bb0, r0 >> 6)], &flags[F(l, bb1, r0 >> 6)]);
                llc_load_2x2(qr + ((long)bb0 * SEQ + r0) * 8,
                             qr + ((long)bb1 * SEQ + r0) * 8,
                             &dA0, &dA1, &dB0, &dB1);
            }
            // phase 0 (batch bb0)
            {
                u32x4 kp0, kp1;
                kp0[0] = dA0[0]; kp0[1] = dA0[1]; kp0[2] = dA1[0]; kp0[3] = dA1[1];
                kp1[0] = dA0[2]; kp1[1] = dA0[3]; kp1[2] = dA1[2]; kp1[3] = dA1[3];
                *(u32x4*)&KbP[0][0][r0] = kp0;
                *(u32x4*)&KbP[0][1][r0] = kp1;
#pragma unroll
                for (int c = 0; c < 8; ++c) {
                    unsigned wa = dA0[c >> 1], wb = dA1[c >> 1];
                    unsigned v = (c & 1) ? ((wa >> 16) | (wb & 0xFFFF0000u))
                                         : ((wa & 0xFFFFu) | (wb << 16));
                    *(unsigned*)&VtH[0][c][r0] = v;
                }
            }
            // phase 1 (batch bb1)
            {
                u32x4 kp0, kp1;
                kp0[0] = dB0[0]; kp0[1] = dB0[1]; kp0[2] = dB1[0]; kp0[3] = dB1[1];
                kp1[0] = dB0[2]; kp1[1] = dB0[3]; kp1[2] = dB1[2]; kp1[3] = dB1[3];
                *(u32x4*)&KbP[1][0][r0] = kp0;
                *(u32x4*)&KbP[1][1][r0] = kp1;
#pragma unroll
                for (int c = 0; c < 8; ++c) {
                    unsigned wa = dB0[c >> 1], wb = dB1[c >> 1];
                    unsigned v = (c & 1) ? ((wa >> 16) | (wb & 0xFFFF0000u))
                                         : ((wa & 0xFFFFu) | (wb << 16));
                    *(unsigned*)&VtH[1][c][r0] = v;
                }
            }
        }
        __syncthreads();

        // ---------------- MFMA both phases: swapped QK^T, fp16 ----------------
        const int qbase = chunk * 64 + qtile * 32;
        for (int ph = 0; ph < 2; ++ph) {
            FragU qfB;
            {
                uint2 qh = KbP[ph][h][qbase + ln];
                unsigned qx = pk_mul_f16(qh.x, B2PK);
                unsigned qy = pk_mul_f16(qh.y, B2PK);
                qfB.u[0] = qx; qfB.u[1] = qy; qfB.u[2] = qx; qfB.u[3] = qy;
            }
            f32x16 zc;
#pragma unroll
            for (int i = 0; i < 16; ++i) zc[i] = 0.f;
            f32x16 accA = zc, accB = zc;
            FragU v1c, v2c;
            {
                const unsigned fill = (ln == 8) ? 0x3C003C00u : 0u;
#pragma unroll
                for (int i = 0; i < 4; ++i) { v1c.u[i] = fill; v2c.u[i] = fill; }
            }

#pragma unroll 2
            for (int t = 0; t < 8; ++t) {
                const int kbase = ((qu << 3) | t) << 5;
                FragU kfA;
                {
                    uint2 kh = KbP[ph][h][kbase + ln];
                    kfA.u[0] = kh.x; kfA.u[1] = kh.y; kfA.u[2] = 0; kfA.u[3] = 0;
                }
                f32x16 s = __builtin_amdgcn_mfma_f32_32x32x16_f16(kfA.s, qfB.s, zc, 0, 0, 0);
                float p[16];
#pragma unroll
                for (int g = 0; g < 16; ++g) p[g] = hw_exp2(s[g]);

                FragU a1, a2;
#pragma unroll
                for (int vi = 0; vi < 4; ++vi) {
                    a1.u[vi] = pkrtz(p[2 * vi], p[2 * vi + 1]);
                    a2.u[vi] = pkrtz(p[8 + 2 * vi], p[8 + 2 * vi + 1]);
                }
                FragU v1h = v1c, v2h = v2c;
                if (ln < 8) {
                    const unsigned* q0 = (const unsigned*)&VtH[ph][ln][kbase + 4 * h];
                    const unsigned* q1 = (const unsigned*)&VtH[ph][ln][kbase + 8 + 4 * h];
                    const unsigned* q2 = (const unsigned*)&VtH[ph][ln][kbase + 16 + 4 * h];
                    const unsigned* q3 = (const unsigned*)&VtH[ph][ln][kbase + 24 + 4 * h];
                    v1h.u[0] = q0[0]; v1h.u[1] = q0[1]; v1h.u[2] = q1[0]; v1h.u[3] = q1[1];
                    v2h.u[0] = q2[0]; v2h.u[1] = q2[1]; v2h.u[2] = q3[0]; v2h.u[3] = q3[1];
                }
                accA = __builtin_amdgcn_mfma_f32_32x32x16_f16(a1.s, v1h.s, accA, 0, 0, 0);
                accB = __builtin_amdgcn_mfma_f32_32x32x16_f16(a2.s, v2h.s, accB, 0, 0, 0);
            }

            if (ln <= 8) {
#pragma unroll
                for (int g = 0; g < 16; ++g)
                    Olds[ph][w][(g & 3) + 8 * (g >> 2) + 4 * h][ln] = accA[g] + accB[g];
            }
        }
        __syncthreads();

        // ---- epilogues: wave 0 -> phase 0, wave 1 -> phase 1, CONCURRENT ----
        if (w < 2) {
            const int ph = w;
            const int bb = bb0 + ph;
            const int r = lane;              // row within chunk (0..63)
            const int rr = r & 31;
            const int w0 = (r >> 5) * 4;
            float o[9];
#pragma unroll
            for (int c = 0; c < 9; ++c)
                o[c] = (Olds[ph][w0][rr][c] + Olds[ph][w0 + 1][rr][c])
                     + (Olds[ph][w0 + 2][rr][c] + Olds[ph][w0 + 3][rr][c]);
            float inv = 1.0f / o[8];
            float outv[8];
#pragma unroll
            for (int c = 0; c < 8; ++c) outv[c] = o[c] * inv;

            const float* W  = attn_w + l * 64; const float* Wb  = attn_b + l * 8;
            const float* g1 = ln1_g + l * 8;   const float* b1v = ln1_b + l * 8;
            const float* W1 = ffn_w1 + l * 64; const float* c1  = ffn_b1 + l * 8;
            const float* W2 = ffn_w2 + l * 64; const float* c2  = ffn_b2 + l * 8;
            const float* g2 = ln2_g + l * 8;   const float* b2v = ln2_b + l * 8;

            float xv[8];
#pragma unroll
            for (int j = 0; j < 8; ++j) xv[j] = x_lds[ph][r][j];

            float y[8]; float m = 0.f;
#pragma unroll
            for (int j = 0; j < 8; ++j) {
                float vv = Wb[j];
#pragma unroll
                for (int i = 0; i < 8; ++i) vv += outv[i] * W[i * 8 + j];
                y[j] = xv[j] + vv;
                m += y[j];
            }
            m *= 0.125f;
            float var = 0.f;
#pragma unroll
            for (int j = 0; j < 8; ++j) { float dd = y[j] - m; var += dd * dd; }
            var *= 0.125f;
            float rsg = rsqrtf(var + LNEPS);
            float xn[8];
#pragma unroll
            for (int j = 0; j < 8; ++j) xn[j] = g1[j] * (y[j] - m) * rsg + b1v[j];

            float hh[8];
#pragma unroll
            for (int j = 0; j < 8; ++j) {
                float vv = c1[j];
#pragma unroll
                for (int i = 0; i < 8; ++i) vv += xn[i] * W1[i * 8 + j];
                hh[j] = vv;
            }
            float qff[8]; qhead(hh, qff);
            float m2 = 0.f;
#pragma unroll
            for (int j = 0; j < 8; ++j) {
                float vv = c2[j];
#pragma unroll
                for (int i = 0; i < 8; ++i) vv += qff[i] * W2[i * 8 + j];
                y[j] = xn[j] + vv;
                m2 += y[j];
            }
            m2 *= 0.125f;
            float var2 = 0.f;
#pragma unroll
            for (int j = 0; j < 8; ++j) { float dd = y[j] - m2; var2 += dd * dd; }
            var2 *= 0.125f;
            float rs2 = rsqrtf(var2 + LNEPS);
#pragma unroll
            for (int j = 0; j < 8; ++j) {
                float xo = g2[j] * (y[j] - m2) * rs2 + b2v[j];
                x_lds[ph][r][j] = xo;
                xv[j] = xo;
            }

            if (l < 5) {
                float z[8]; qhead(xv, z);
                u32x4 pz;
                pz[0] = pkrtz(z[0], z[1]); pz[1] = pkrtz(z[2], z[3]);
                pz[2] = pkrtz(z[4], z[5]); pz[3] = pkrtz(z[6], z[7]);
                llc_store_row16(qw + ((long)bb * SEQ + chunk * 64 + r) * 8, pz);
                // wave-level release: vmcnt covers all 64 lanes' stores
                asm volatile("s_waitcnt vmcnt(0)" ::: "memory");
                if (r == 0) sys_store_u32(&flags[F(l + 1, bb, chunk)], 1u);
            }
        }
        // no barrier: next stage writes KbP/VtH (disjoint from Olds/x_lds
        // read by epilogues); epilogue waves reach next barrier after their
        // own epi+stage, ordering everything before the next MFMA.
    }

    // ---------------- pool + classifier (per phase, fence-free) ----------------
    if ((tid >> 6) < 2) {
        const int ph = tid >> 6;
        const int r = tid & 63;
        const int bb = bb0 + ph;
        float a[8];
#pragma unroll
        for (int j = 0; j < 8; ++j) {
            a[j] = x_lds[ph][r][j];
#pragma unroll
            for (int off = 1; off <= 32; off <<= 1) a[j] += __shfl_xor(a[j], off);
        }
        if (r < 8) sys_store(&partial[(bb * 16 + chunk) * 8 + r], a[r]);
    }
    asm volatile("s_waitcnt vmcnt(0)" ::: "memory");
    __syncthreads();
    if (tid == 0) {
        unsigned r = __hip_atomic_fetch_add(&pcnt[bb0 * 16], 1u,
                                            __ATOMIC_RELAXED, __HIP_MEMORY_SCOPE_AGENT);
        isL[0] = (r == 15u);
    }
    if (tid == 64) {
        unsigned r = __hip_atomic_fetch_add(&pcnt[bb1 * 16], 1u,
                                            __ATOMIC_RELAXED, __HIP_MEMORY_SCOPE_AGENT);
        isL[1] = (r == 15u);
    }
    __syncthreads();
    if ((tid >> 6) < 2) {
        const int ph = tid >> 6;
        if (isL[ph]) {
            const int bb = bb0 + ph;
            const int lr = tid & 63;
            int g = lr >> 3, j = lr & 7;
            float s = sys_load(&partial[(bb * 16 + g) * 8 + j])
                    + sys_load(&partial[(bb * 16 + g + 8) * 8 + j]);
            s += __shfl_xor(s, 8); s += __shfl_xor(s, 16); s += __shfl_xor(s, 32);
            float poolj = s * (1.0f / 1024.0f);
            int c = lr < 10 ? lr : 9;
            float o = cls_b[c];
#pragma unroll
            for (int j2 = 0; j2 < 8; ++j2)
                o += __shfl(poolj, j2) * cls_w[j2 * 10 + c];
            if (lr < 10) out[bb * 10 + lr] = o;
        }
    }
}

extern "C" void kernel_launch(void* const* d_in, const int* in_sizes, int n_in,
                              void* d_out, int out_size, void* d_ws, size_t ws_size,
                              hipStream_t stream) {
    const int*   tokens = (const int*)d_in[0];
    const float* emb    = (const float*)d_in[1];
    const float* ln1_g  = (const float*)d_in[2];
    const float* ln1_b  = (const float*)d_in[3];
    const float* ln2_g  = (const float*)d_in[4];
    const float* ln2_b  = (const float*)d_in[5];
    const float* attn_w = (const float*)d_in[6];
    const float* attn_b = (const float*)d_in[7];
    const float* ffn_w1 = (const float*)d_in[8];
    const float* ffn_b1 = (const float*)d_in[9];
    const float* ffn_w2 = (const float*)d_in[10];
    const float* ffn_b2 = (const float*)d_in[11];
    const float* cls_w  = (const float*)d_in[12];
    const float* cls_b  = (const float*)d_in[13];

    // ws (u32 words): flags 3072 | pcnt 512 | partial 4096 f32 | qkv0/1 (u16)
    unsigned*       flags   = (unsigned*)d_ws;
    unsigned*       pcnt    = flags + 3072;
    float*          partial = (float*)(pcnt + 512);
    unsigned short* qkv0    = (unsigned short*)(partial + 4096);
    unsigned short* qkv1    = qkv0 + (long)NROWS * 8;
    float*          outp    = (float*)d_out;

    zero_flags<<<1, 1024, 0, stream>>>(flags);   // zeroes flags + pcnt
    qt_fused<<<256, 512, 0, stream>>>(
        tokens, emb, attn_w, attn_b, ln1_g, ln1_b,
        ffn_w1, ffn_b1, ffn_w2, ffn_b2, ln2_g, ln2_b,
        cls_w, cls_b, qkv0, qkv1, flags, pcnt, partial, outp);
}

// Round 18
// 75.332 us; speedup vs baseline: 1.0972x; 1.0972x over previous
//
#include <hip/hip_runtime.h>
#include <math.h>

#define EMB 8
#define SEQ 1024
#define NBATCH 32
#define NROWS (NBATCH * SEQ)
#define LNEPS 1e-5f
#define F(l, b, c) (((l) * 32 + (b)) * 16 + (c))

typedef __attribute__((ext_vector_type(4))) unsigned u32x4;
typedef __attribute__((ext_vector_type(8))) _Float16 f16x8;
typedef __attribute__((ext_vector_type(16))) float f32x16;

union FragU { unsigned u[4]; f16x8 s; };

__device__ __forceinline__ unsigned pkrtz(float a, float b) {
    unsigned r;
    asm("v_cvt_pkrtz_f16_f32 %0, %1, %2" : "=v"(r) : "v"(a), "v"(b));
    return r;
}
__device__ __forceinline__ unsigned pk_mul_f16(unsigned a, unsigned b) {
    unsigned r;
    asm("v_pk_mul_f16 %0, %1, %2" : "=v"(r) : "v"(a), "v"(b));
    return r;
}
// Bare hardware 2^x (v_exp_f32) — R13-proven 25 µs win vs __ocml_exp2_f32.
__device__ __forceinline__ float hw_exp2(float x) {
    return __builtin_amdgcn_exp2f(x);
}

// LLC-coherent (sc0 sc1) accessors: bypass L1/L2, land at the cross-XCD
// coherence point. No cache-wide maintenance anywhere.
__device__ __forceinline__ void llc_load_2rows(const unsigned short* p,
                                               u32x4* d0, u32x4* d1) {
    asm volatile(
        "global_load_dwordx4 %0, %[a], off sc0 sc1\n\t"
        "global_load_dwordx4 %1, %[a], off offset:16 sc0 sc1\n\t"
        "s_waitcnt vmcnt(0)"
        : "=&v"(*d0), "=&v"(*d1) : [a] "v"(p) : "memory");
}
__device__ __forceinline__ void llc_store_row16(unsigned short* p, u32x4 v) {
    asm volatile("global_store_dwordx4 %[a], %[x], off sc0 sc1"
                 :: [a] "v"(p), [x] "v"(v) : "memory");
}
__device__ __forceinline__ void sys_store(float* p, float v) {
    asm volatile("global_store_dword %0, %1, off sc0 sc1" :: "v"(p), "v"(v) : "memory");
}
__device__ __forceinline__ float sys_load(const float* p) {
    float r;
    asm volatile("global_load_dword %0, %1, off sc0 sc1\n\ts_waitcnt vmcnt(0)"
                 : "=v"(r) : "v"(p) : "memory");
    return r;
}
__device__ __forceinline__ unsigned sys_load_u32(const unsigned* p) {
    unsigned r;
    asm volatile("global_load_dword %0, %1, off sc0 sc1\n\ts_waitcnt vmcnt(0)"
                 : "=v"(r) : "v"(p) : "memory");
    return r;
}
__device__ __forceinline__ void sys_store_u32(unsigned* p, unsigned v) {
    asm volatile("global_store_dword %0, %1, off sc0 sc1" :: "v"(p), "v"(v) : "memory");
}

// Closed-form quantum head: RX layer + Clifford (CNOT chain + H) conjugates
// each Z_i into a product of cos(x_j) (even/odd prefix products).
__device__ __forceinline__ void qhead(const float xv[8], float z[8]) {
    float c[8];
#pragma unroll
    for (int j = 0; j < 8; ++j) c[j] = __cosf(xv[j]);
    float e0 = c[0];
    float o1 = c[1];
    float e2 = e0 * c[2];
    float o3 = o1 * c[3];
    float e4 = e2 * c[4];
    float o5 = o3 * c[5];
    float e6 = e4 * c[6];
    z[0] = e0; z[1] = o1; z[2] = e2; z[3] = o3;
    z[4] = e4; z[5] = o5; z[6] = e6;
    z[7] = e6 * o5 * c[7];
}

__device__ __forceinline__ void embed_row(const int* __restrict__ tokens,
                                          const float* __restrict__ emb,
                                          long grow, int srow, float xv[8]) {
    int tok = tokens[grow];
    const float* e = emb + (long)tok * EMB;
    float p = (float)srow;
    xv[0] = e[0] + sinf(p);
    xv[1] = e[1] + cosf(p);
    xv[2] = e[2] + sinf(p * 0.1f);
    xv[3] = e[3] + cosf(p * 0.1f);
    xv[4] = e[4] + sinf(p * 0.01f);
    xv[5] = e[5] + cosf(p * 0.01f);
    xv[6] = e[6] + sinf(p * 0.001f);
    xv[7] = e[7] + cosf(p * 0.001f);
}

// Flags must be zero at kernel start each call (harness poisons ws once).
__global__ __launch_bounds__(1024) void zero_flags(unsigned* __restrict__ f) {
    for (int i = threadIdx.x; i < 3584; i += 1024) f[i] = 0u;
}

// Whole model, one persistent kernel — R16 champion (75.5 µs): 256 WGs x
// 512 thr, 64-row chunks, 2-batch phase pipeline, fp16 qkv handoff.
// Producers store rows as 16B packed fp16; staging is pure bit-moves;
// beta^2 = log2e/sqrt(8) folded into Q once per phase via v_pk_mul_f16.
__global__ __launch_bounds__(512, 2) void qt_fused(
    const int* __restrict__ tokens, const float* __restrict__ emb,
    const float* __restrict__ attn_w, const float* __restrict__ attn_b,
    const float* __restrict__ ln1_g, const float* __restrict__ ln1_b,
    const float* __restrict__ ffn_w1, const float* __restrict__ ffn_b1,
    const float* __restrict__ ffn_w2, const float* __restrict__ ffn_b2,
    const float* __restrict__ ln2_g, const float* __restrict__ ln2_b,
    const float* __restrict__ cls_w, const float* __restrict__ cls_b,
    unsigned short* __restrict__ qkv0, unsigned short* __restrict__ qkv1,
    unsigned* __restrict__ flags, unsigned* __restrict__ pcnt,
    float* __restrict__ partial, float* __restrict__ out)
{
    __shared__ __align__(16) uint2 KbP[2][1024];          // 16 KB fp16(z), [h][row]
    __shared__ __align__(16) unsigned short VtH[8][1032]; // 16.5 KB fp16(z) transposed
    __shared__ float Olds[8][32][9];                      // 9.2 KB PV partials
    __shared__ float x_lds[2][64][8];                     // 4 KB residual stream
    __shared__ int isL[2];

    const int bid = blockIdx.x;
    const int group = bid & 15;     // group's 16 WGs share an XCD (round-robin)
    const int chunk = bid >> 4;     // 0..15, rows [chunk*64, chunk*64+64)
    const int tid = threadIdx.x;

    const int w = tid >> 6;
    const int lane = tid & 63;
    const int ln = lane & 31;
    const int h = lane >> 5;
    const int qtile = w >> 2;       // 0..1
    const int qu = w & 3;           // key quarter
    const int r0 = tid * 2;         // this thread's 2 staging rows
    const unsigned B2PK = pkrtz(0.51006972f, 0.51006972f);  // log2e/sqrt(8)

    for (int l = 0; l < 6; ++l) {
        const unsigned short* qr = (l & 1) ? qkv1 : qkv0;
        unsigned short* qw = (l & 1) ? qkv0 : qkv1;
        for (int ph = 0; ph < 2; ++ph) {
            const int bb = group * 2 + ph;
            // ---------------- stage: rows r0, r0+1 (bit-moves only) ----------------
            {
                u32x4 d0, d1;
                if (l == 0) {
                    float e0[8], e1[8], z0[8], z1[8];
                    embed_row(tokens, emb, (long)bb * SEQ + r0, r0, e0);
                    embed_row(tokens, emb, (long)bb * SEQ + r0 + 1, r0 + 1, e1);
                    if ((r0 >> 6) == chunk) {
                        const int lr = r0 - chunk * 64;
#pragma unroll
                        for (int j = 0; j < 8; ++j) {
                            x_lds[ph][lr][j] = e0[j];
                            x_lds[ph][lr + 1][j] = e1[j];
                        }
                    }
                    qhead(e0, z0); qhead(e1, z1);
                    d0[0] = pkrtz(z0[0], z0[1]); d0[1] = pkrtz(z0[2], z0[3]);
                    d0[2] = pkrtz(z0[4], z0[5]); d0[3] = pkrtz(z0[6], z0[7]);
                    d1[0] = pkrtz(z1[0], z1[1]); d1[1] = pkrtz(z1[2], z1[3]);
                    d1[2] = pkrtz(z1[4], z1[5]); d1[3] = pkrtz(z1[6], z1[7]);
                } else {
                    // per-thread dataflow wait on this thread's producer only
                    const unsigned* fp = &flags[F(l, bb, r0 >> 6)];
                    while (sys_load_u32(fp) == 0u) __builtin_amdgcn_s_sleep(1);
                    llc_load_2rows(qr + ((long)bb * SEQ + r0) * 8, &d0, &d1);
                }
                u32x4 kp0, kp1;
                kp0[0] = d0[0]; kp0[1] = d0[1]; kp0[2] = d1[0]; kp0[3] = d1[1];
                kp1[0] = d0[2]; kp1[1] = d0[3]; kp1[2] = d1[2]; kp1[3] = d1[3];
                *(u32x4*)&KbP[0][r0] = kp0;
                *(u32x4*)&KbP[1][r0] = kp1;
#pragma unroll
                for (int c = 0; c < 8; ++c) {
                    unsigned wa = d0[c >> 1], wb = d1[c >> 1];
                    unsigned v = (c & 1) ? ((wa >> 16) | (wb & 0xFFFF0000u))
                                         : ((wa & 0xFFFFu) | (wb << 16));
                    *(unsigned*)&VtH[c][r0] = v;
                }
            }
            __syncthreads();

            // ---------------- MFMA: swapped QK^T, fp16 ----------------
            const int qbase = chunk * 64 + qtile * 32;
            FragU qfB;
            {
                uint2 qh = KbP[h][qbase + ln];
                unsigned qx = pk_mul_f16(qh.x, B2PK);
                unsigned qy = pk_mul_f16(qh.y, B2PK);
                qfB.u[0] = qx; qfB.u[1] = qy; qfB.u[2] = qx; qfB.u[3] = qy;
            }
            f32x16 zc;
#pragma unroll
            for (int i = 0; i < 16; ++i) zc[i] = 0.f;
            f32x16 accA = zc, accB = zc;
            // loop-invariant V-frags for lanes ln>=8 (ones column / zeros)
            FragU v1c, v2c;
            {
                const unsigned fill = (ln == 8) ? 0x3C003C00u : 0u;
#pragma unroll
                for (int i = 0; i < 4; ++i) { v1c.u[i] = fill; v2c.u[i] = fill; }
            }

#pragma unroll 2
            for (int t = 0; t < 8; ++t) {
                const int kbase = ((qu << 3) | t) << 5;
                FragU kfA;
                {
                    uint2 kh = KbP[h][kbase + ln];
                    kfA.u[0] = kh.x; kfA.u[1] = kh.y; kfA.u[2] = 0; kfA.u[3] = 0;
                }
                f32x16 s = __builtin_amdgcn_mfma_f32_32x32x16_f16(kfA.s, qfB.s, zc, 0, 0, 0);
                float p[16];
#pragma unroll
                for (int g = 0; g < 16; ++g) p[g] = hw_exp2(s[g]);

                FragU a1, a2;
#pragma unroll
                for (int vi = 0; vi < 4; ++vi) {
                    a1.u[vi] = pkrtz(p[2 * vi], p[2 * vi + 1]);
                    a2.u[vi] = pkrtz(p[8 + 2 * vi], p[8 + 2 * vi + 1]);
                }
                FragU v1h = v1c, v2h = v2c;
                if (ln < 8) {
                    const unsigned* q0 = (const unsigned*)&VtH[ln][kbase + 4 * h];
                    const unsigned* q1 = (const unsigned*)&VtH[ln][kbase + 8 + 4 * h];
                    const unsigned* q2 = (const unsigned*)&VtH[ln][kbase + 16 + 4 * h];
                    const unsigned* q3 = (const unsigned*)&VtH[ln][kbase + 24 + 4 * h];
                    v1h.u[0] = q0[0]; v1h.u[1] = q0[1]; v1h.u[2] = q1[0]; v1h.u[3] = q1[1];
                    v2h.u[0] = q2[0]; v2h.u[1] = q2[1]; v2h.u[2] = q3[0]; v2h.u[3] = q3[1];
                }
                accA = __builtin_amdgcn_mfma_f32_32x32x16_f16(a1.s, v1h.s, accA, 0, 0, 0);
                accB = __builtin_amdgcn_mfma_f32_32x32x16_f16(a2.s, v2h.s, accB, 0, 0, 0);
            }

            if (ln <= 8) {
#pragma unroll
                for (int g = 0; g < 16; ++g)
                    Olds[w][(g & 3) + 8 * (g >> 2) + 4 * h][ln] = accA[g] + accB[g];
            }
            __syncthreads();

            // ---- epilogue by wave `ph` (concurrent with next phase's stage) ----
            if ((tid >> 6) == ph) {
                const int r = tid & 63;
                const int rr = r & 31;
                const int w0 = (r >> 5) * 4;
                float o[9];
#pragma unroll
                for (int c = 0; c < 9; ++c)
                    o[c] = (Olds[w0][rr][c] + Olds[w0 + 1][rr][c])
                         + (Olds[w0 + 2][rr][c] + Olds[w0 + 3][rr][c]);
                float inv = 1.0f / o[8];
                float outv[8];
#pragma unroll
                for (int c = 0; c < 8; ++c) outv[c] = o[c] * inv;

                const float* W  = attn_w + l * 64; const float* Wb  = attn_b + l * 8;
                const float* g1 = ln1_g + l * 8;   const float* b1v = ln1_b + l * 8;
                const float* W1 = ffn_w1 + l * 64; const float* c1  = ffn_b1 + l * 8;
                const float* W2 = ffn_w2 + l * 64; const float* c2  = ffn_b2 + l * 8;
                const float* g2 = ln2_g + l * 8;   const float* b2v = ln2_b + l * 8;

                float xv[8];
#pragma unroll
                for (int j = 0; j < 8; ++j) xv[j] = x_lds[ph][r][j];

                float y[8]; float m = 0.f;
#pragma unroll
                for (int j = 0; j < 8; ++j) {
                    float vv = Wb[j];
#pragma unroll
                    for (int i = 0; i < 8; ++i) vv += outv[i] * W[i * 8 + j];
                    y[j] = xv[j] + vv;
                    m += y[j];
                }
                m *= 0.125f;
                float var = 0.f;
#pragma unroll
                for (int j = 0; j < 8; ++j) { float dd = y[j] - m; var += dd * dd; }
                var *= 0.125f;
                float rsg = rsqrtf(var + LNEPS);
                float xn[8];
#pragma unroll
                for (int j = 0; j < 8; ++j) xn[j] = g1[j] * (y[j] - m) * rsg + b1v[j];

                float hh[8];
#pragma unroll
                for (int j = 0; j < 8; ++j) {
                    float vv = c1[j];
#pragma unroll
                    for (int i = 0; i < 8; ++i) vv += xn[i] * W1[i * 8 + j];
                    hh[j] = vv;
                }
                float qff[8]; qhead(hh, qff);
                float m2 = 0.f;
#pragma unroll
                for (int j = 0; j < 8; ++j) {
                    float vv = c2[j];
#pragma unroll
                    for (int i = 0; i < 8; ++i) vv += qff[i] * W2[i * 8 + j];
                    y[j] = xn[j] + vv;
                    m2 += y[j];
                }
                m2 *= 0.125f;
                float var2 = 0.f;
#pragma unroll
                for (int j = 0; j < 8; ++j) { float dd = y[j] - m2; var2 += dd * dd; }
                var2 *= 0.125f;
                float rs2 = rsqrtf(var2 + LNEPS);
#pragma unroll
                for (int j = 0; j < 8; ++j) {
                    float xo = g2[j] * (y[j] - m2) * rs2 + b2v[j];
                    x_lds[ph][r][j] = xo;
                    xv[j] = xo;
                }

                if (l < 5) {
                    float z[8]; qhead(xv, z);
                    u32x4 pz;
                    pz[0] = pkrtz(z[0], z[1]); pz[1] = pkrtz(z[2], z[3]);
                    pz[2] = pkrtz(z[4], z[5]); pz[3] = pkrtz(z[6], z[7]);
                    llc_store_row16(qw + ((long)bb * SEQ + chunk * 64 + r) * 8, pz);
                    // wave-level release: vmcnt covers all 64 lanes' stores
                    asm volatile("s_waitcnt vmcnt(0)" ::: "memory");
                    if (r == 0) sys_store_u32(&flags[F(l + 1, bb, chunk)], 1u);
                }
            }
            // no barrier: next stage's KbP writes ordered by Olds barrier;
            // epilogue's Olds reads ordered before next MFMA by next phase's
            // post-stage barrier.
        }
    }

    // ---------------- pool + classifier (per phase, fence-free) ----------------
    if ((tid >> 6) < 2) {
        const int ph = tid >> 6;
        const int r = tid & 63;
        const int bb = group * 2 + ph;
        float a[8];
#pragma unroll
        for (int j = 0; j < 8; ++j) {
            a[j] = x_lds[ph][r][j];
#pragma unroll
            for (int off = 1; off <= 32; off <<= 1) a[j] += __shfl_xor(a[j], off);
        }
        if (r < 8) sys_store(&partial[(bb * 16 + chunk) * 8 + r], a[r]);
    }
    asm volatile("s_waitcnt vmcnt(0)" ::: "memory");
    __syncthreads();
    if (tid == 0) {
        unsigned r = __hip_atomic_fetch_add(&pcnt[(group * 2) * 16], 1u,
                                            __ATOMIC_RELAXED, __HIP_MEMORY_SCOPE_AGENT);
        isL[0] = (r == 15u);
    }
    if (tid == 64) {
        unsigned r = __hip_atomic_fetch_add(&pcnt[(group * 2 + 1) * 16], 1u,
                                            __ATOMIC_RELAXED, __HIP_MEMORY_SCOPE_AGENT);
        isL[1] = (r == 15u);
    }
    __syncthreads();
    if ((tid >> 6) < 2) {
        const int ph = tid >> 6;
        if (isL[ph]) {
            const int bb = group * 2 + ph;
            const int lr = tid & 63;
            int g = lr >> 3, j = lr & 7;
            float s = sys_load(&partial[(bb * 16 + g) * 8 + j])
                    + sys_load(&partial[(bb * 16 + g + 8) * 8 + j]);
            s += __shfl_xor(s, 8); s += __shfl_xor(s, 16); s += __shfl_xor(s, 32);
            float poolj = s * (1.0f / 1024.0f);
            int c = lr < 10 ? lr : 9;
            float o = cls_b[c];
#pragma unroll
            for (int j2 = 0; j2 < 8; ++j2)
                o += __shfl(poolj, j2) * cls_w[j2 * 10 + c];
            if (lr < 10) out[bb * 10 + lr] = o;
        }
    }
}

extern "C" void kernel_launch(void* const* d_in, const int* in_sizes, int n_in,
                              void* d_out, int out_size, void* d_ws, size_t ws_size,
                              hipStream_t stream) {
    const int*   tokens = (const int*)d_in[0];
    const float* emb    = (const float*)d_in[1];
    const float* ln1_g  = (const float*)d_in[2];
    const float* ln1_b  = (const float*)d_in[3];
    const float* ln2_g  = (const float*)d_in[4];
    const float* ln2_b  = (const float*)d_in[5];
    const float* attn_w = (const float*)d_in[6];
    const float* attn_b = (const float*)d_in[7];
    const float* ffn_w1 = (const float*)d_in[8];
    const float* ffn_b1 = (const float*)d_in[9];
    const float* ffn_w2 = (const float*)d_in[10];
    const float* ffn_b2 = (const float*)d_in[11];
    const float* cls_w  = (const float*)d_in[12];
    const float* cls_b  = (const float*)d_in[13];

    // ws (u32 words): flags 3072 | pcnt 512 | partial 4096 f32 | qkv0/1 (u16)
    unsigned*       flags   = (unsigned*)d_ws;
    unsigned*       pcnt    = flags + 3072;
    float*          partial = (float*)(pcnt + 512);
    unsigned short* qkv0    = (unsigned short*)(partial + 4096);
    unsigned short* qkv1    = qkv0 + (long)NROWS * 8;
    float*          outp    = (float*)d_out;

    zero_flags<<<1, 1024, 0, stream>>>(flags);   // zeroes flags + pcnt
    qt_fused<<<256, 512, 0, stream>>>(
        tokens, emb, attn_w, attn_b, ln1_g, ln1_b,
        ffn_w1, ffn_b1, ffn_w2, ffn_b2, ln2_g, ln2_b,
        cls_w, cls_b, qkv0, qkv1, flags, pcnt, partial, outp);
}